// Round 8
// baseline (643.909 us; speedup 1.0000x reference)
//
#include <hip/hip_runtime.h>
#include <cstdint>
#include <cstddef>

#define IN_F 8192
#define OUT_F 8192
#define BATCH 512
#define KSPLIT 4
#define KSLICE (IN_F / KSPLIT) /* 2048 */
#define BK 32
#define TILES (KSLICE / BK) /* 64 */
#define BM 128
#define BN 128

typedef __bf16 bf16x8 __attribute__((ext_vector_type(8)));
typedef float floatx4 __attribute__((ext_vector_type(4)));

// fp32 -> bf16 round-to-nearest-even
__device__ __forceinline__ ushort f2bf(float f) {
  uint32_t u = __float_as_uint(f);
  u += 0x7FFFu + ((u >> 16) & 1u);
  return (ushort)(u >> 16);
}

// packed int (2 nibbles in low byte) -> bf16x2 of biased weights (q+136):
// low half = 0x4300|hi_nib (even k), high half = 0x4300|lo_nib (odd k)
__device__ __forceinline__ uint32_t dq(uint32_t u) {
  return (((u | (u << 20)) >> 4) & 0x000F000Fu) | 0x43004300u;
}

// 4 packed ints (16B, one B-fragment) -> bf16x8 biased weight fragment
__device__ __forceinline__ bf16x8 dq8(int4 p) {
  int4 u;
  u.x = (int)dq((uint32_t)p.x); u.y = (int)dq((uint32_t)p.y);
  u.z = (int)dq((uint32_t)p.z); u.w = (int)dq((uint32_t)p.w);
  return *(bf16x8*)&u;
}

// async global->LDS, 16B/lane, LDS dest = wave-uniform base + lane*16
__device__ __forceinline__ void gl16(const void* g, uint32_t* l) {
  __builtin_amdgcn_global_load_lds(
      (const __attribute__((address_space(1))) uint32_t*)g,
      (__attribute__((address_space(3))) uint32_t*)l, 16, 0, 0);
}

// Pass 1: x fp32 -> bf16, per-slice rowsums (KSPLIT=4). Zeroes out only on
// the atomic-fallback path (zout != nullptr).
__global__ __launch_bounds__(256) void cvt_rowsum(const float* __restrict__ x,
                                                  ushort* __restrict__ xb,
                                                  float* __restrict__ rowsum,
                                                  float* __restrict__ zout) {
  const int b = blockIdx.x;
  const int t = threadIdx.x;
  const float4* xr = (const float4*)(x + (size_t)b * IN_F);
  ushort4* xo = (ushort4*)(xb + (size_t)b * IN_F);
  float s[4] = {0.f, 0.f, 0.f, 0.f};
#pragma unroll
  for (int i = 0; i < 8; ++i) {
    float4 v = xr[i * 256 + t];
    ushort4 o;
    o.x = f2bf(v.x); o.y = f2bf(v.y); o.z = f2bf(v.z); o.w = f2bf(v.w);
    xo[i * 256 + t] = o;
    if (zout) {
      float4 z = {0.f, 0.f, 0.f, 0.f};
      ((float4*)(zout + (size_t)b * OUT_F))[i * 256 + t] = z;
    }
    s[i >> 1] += __uint_as_float((uint32_t)o.x << 16) + __uint_as_float((uint32_t)o.y << 16)
               + __uint_as_float((uint32_t)o.z << 16) + __uint_as_float((uint32_t)o.w << 16);
  }
  __shared__ float red[4][4];
  const int lane = t & 63, wid = t >> 6;
#pragma unroll
  for (int j = 0; j < 4; ++j) {
    float v = s[j];
#pragma unroll
    for (int off = 32; off >= 1; off >>= 1) v += __shfl_down(v, off, 64);
    if (lane == 0) red[wid][j] = v;
  }
  __syncthreads();
  if (t < 4) rowsum[t * BATCH + b] = red[0][t] + red[1][t] + red[2][t] + red[3][t];
}

// Split-K(4) quantized GEMM, 128(m) x 128(n) x (BK=32), 256 thr, 4 waves
// (2m x 2n), per-wave 64x64 (acc[4][4]).
// Same verified TILE machinery as r7 (B in regs depth-2 + in-register dq,
// A via gl16 into 4 rotating 8KB swizzled slots, one counted vmcnt(6) + one
// s_barrier per tile) -- but partitioned into 4-wave blocks, grid 1024 =
// 4 INDEPENDENT BARRIER DOMAINS PER CU (16 waves/CU). r0-r7 all ran one
// barrier domain/CU, so the front region (dq+ds_read+issue) left the MFMA
// pipe idle with nothing to interleave; 4 domains let blocks phase-slide.
__global__ __launch_bounds__(256, 4) void qgemm(const ushort* __restrict__ xb,
                                                const int* __restrict__ pw,
                                                const float* __restrict__ scale,
                                                const float* __restrict__ rowsum,
                                                float* __restrict__ out,
                                                float* __restrict__ part) {
  __shared__ uint32_t As[4 * 128 * 16];  // 4 slots x 8 KB = 32 KB

  const int tid = threadIdx.x;
  const int lane = tid & 63;
  const int w = tid >> 6;           // 0..3
  const int wm = w >> 1, wn = w & 1;
  const int lr = lane & 15, lq = lane >> 4;

  const int n0 = blockIdx.x * BN;
  const int m0 = blockIdx.y * BM;
  const int ks = blockIdx.z;

  // A gl16 source: lane l -> row base+(l>>2), pos l&3; stored chunk at
  // (row,p) is p ^ ((row>>1)&3) -> fold key (l>>3)&3 into the source addr.
  const int swz = ((lane & 3) ^ ((lane >> 3) & 3)) * 16;
  const char* aSrc0 = (const char*)xb
      + (size_t)(m0 + w * 32 + (lane >> 2)) * (IN_F * 2)
      + (size_t)ks * (KSLICE * 2) + swz;

  // B fragment pointers: frag f at row n0+wn*64+f*16+lr, 16B at col lq*16
  // (+ t*64 per tile). Packed row = IN_F*2 bytes (2B/weight).
  const char* bbase = (const char*)pw + (size_t)(n0 + wn * 64 + lr) * (IN_F * 2)
      + (size_t)ks * (KSLICE * 2) + lq * 16;
  const char* bp0 = bbase;
  const char* bp1 = bbase + (size_t)16 * (IN_F * 2);
  const char* bp2 = bbase + (size_t)32 * (IN_F * 2);
  const char* bp3 = bbase + (size_t)48 * (IN_F * 2);

  // A fragment reads: row = wm*64 + f*16 + lr, chunk lq ^ ((lr>>1)&3)
  const int key = (lr >> 1) & 3;
  const int aBase = wm * 1024 + lr * 16 + ((lq ^ key) * 4);  // + f*256

  floatx4 acc[4][4] = {};

#define VMW6() asm volatile("s_waitcnt vmcnt(6)" ::: "memory")
#define VMW0() asm volatile("s_waitcnt vmcnt(0)" ::: "memory")
#define BAR() asm volatile("s_barrier" ::: "memory")

  // One K-tile. P0..P3: packed B(tt) in regs (consumed, then refilled with
  // B(tt+2) when ISS). A(tt) is published in slot tt&3 at entry.
#define TILE(tt, P0, P1, P2, P3, ISS)                                        \
  {                                                                          \
    const uint32_t* sA = As + (((tt) & 3) * 2048) + aBase;                   \
    bf16x8 av[4], bv[4];                                                     \
    bv[0] = dq8(P0); bv[1] = dq8(P1); bv[2] = dq8(P2); bv[3] = dq8(P3);      \
    _Pragma("unroll") for (int f = 0; f < 4; ++f)                            \
        av[f] = *(const bf16x8*)(sA + f * 256);                              \
    if (ISS) {                                                               \
      const size_t co = (size_t)((tt) + 2) * 64;                             \
      P0 = *(const int4*)(bp0 + co); P1 = *(const int4*)(bp1 + co);          \
      P2 = *(const int4*)(bp2 + co); P3 = *(const int4*)(bp3 + co);          \
      const char* as_ = aSrc0 + co;                                          \
      uint32_t* ad_ = As + ((((tt) + 2) & 3) * 2048) + w * 512;              \
      gl16(as_, ad_);                                                        \
      gl16(as_ + 262144, ad_ + 256);                                         \
    }                                                                        \
    __builtin_amdgcn_s_setprio(1);                                           \
    _Pragma("unroll") for (int f = 0; f < 4; ++f)                            \
        _Pragma("unroll") for (int fn = 0; fn < 4; ++fn)                     \
            acc[f][fn] = __builtin_amdgcn_mfma_f32_16x16x32_bf16(            \
                av[f], bv[fn], acc[f][fn], 0, 0, 0);                         \
    __builtin_amdgcn_s_setprio(0);                                           \
  }

  int4 pE0, pE1, pE2, pE3, pO0, pO1, pO2, pO3;

  // ---- prologue: B(0)->E, A(0)->slot0, B(1)->O, A(1)->slot1 ----
  {
    uint32_t* aD = As + w * 512;
    pE0 = *(const int4*)(bp0); pE1 = *(const int4*)(bp1);
    pE2 = *(const int4*)(bp2); pE3 = *(const int4*)(bp3);
    gl16(aSrc0, aD);
    gl16(aSrc0 + 262144, aD + 256);
    pO0 = *(const int4*)(bp0 + 64); pO1 = *(const int4*)(bp1 + 64);
    pO2 = *(const int4*)(bp2 + 64); pO3 = *(const int4*)(bp3 + 64);
    gl16(aSrc0 + 64, aD + 2048);
    gl16(aSrc0 + 64 + 262144, aD + 2048 + 256);
    VMW6();  // oldest 6 = B(0)+A(0) landed; B(1)+A(1) stay in flight
    BAR();
  }

  // ---- steady state: tiles 0..61 issue prefetch for t+2 ----
  for (int t = 0; t <= TILES - 4; t += 2) {
    TILE(t, pE0, pE1, pE2, pE3, true);
    VMW6();  // B(t+1)+A(t+1) landed; t+2's 6 ops in flight
    BAR();
    TILE(t + 1, pO0, pO1, pO2, pO3, true);
    VMW6();
    BAR();
  }
  // ---- tail: tiles 62 (E) and 63 (O), no new staging ----
  TILE(TILES - 2, pE0, pE1, pE2, pE3, false);
  VMW0();  // drain B(63)+A(63)
  BAR();
  TILE(TILES - 1, pO0, pO1, pO2, pO3, false);

  // epilogue: C/D layout col=lane&15, row=(lane>>4)*4+reg
  const int omb = m0 + wm * 64 + lq * 4;
  const int on = n0 + wn * 64 + lr;
  float scv[4];
#pragma unroll
  for (int fn = 0; fn < 4; ++fn) scv[fn] = scale[on + fn * 16];
  float rsv[4][4];
#pragma unroll
  for (int mi = 0; mi < 4; ++mi)
#pragma unroll
    for (int rr = 0; rr < 4; ++rr)
      rsv[mi][rr] = rowsum[ks * BATCH + omb + mi * 16 + rr];

  if (part) {
    float* dst = (ks == 0) ? out : (part + (size_t)(ks - 1) * BATCH * OUT_F);
#pragma unroll
    for (int mi = 0; mi < 4; ++mi)
#pragma unroll
      for (int fn = 0; fn < 4; ++fn) {
        const float s = scv[fn];
        float* op = dst + (size_t)(omb + mi * 16) * OUT_F + (on + fn * 16);
#pragma unroll
        for (int rr = 0; rr < 4; ++rr)
          op[(size_t)rr * OUT_F] = s * (acc[mi][fn][rr] - 136.f * rsv[mi][rr]);
      }
  } else {
#pragma unroll
    for (int mi = 0; mi < 4; ++mi)
#pragma unroll
      for (int fn = 0; fn < 4; ++fn) {
        const float s = scv[fn];
        float* op = out + (size_t)(omb + mi * 16) * OUT_F + (on + fn * 16);
#pragma unroll
        for (int rr = 0; rr < 4; ++rr)
          atomicAdd(op + (size_t)rr * OUT_F, s * (acc[mi][fn][rr] - 136.f * rsv[mi][rr]));
      }
  }
#undef TILE
#undef VMW6
#undef VMW0
#undef BAR
}

// out += p0 + p1 + p2, grid-strided float4
__global__ __launch_bounds__(256) void reduce_add(float* __restrict__ out,
                                                  const float* __restrict__ part) {
  const size_t n = (size_t)BATCH * OUT_F / 4;
  float4* o4 = (float4*)out;
  const float4* p0 = (const float4*)part;
  const float4* p1 = p0 + n;
  const float4* p2 = p1 + n;
  for (size_t i = (size_t)blockIdx.x * 256 + threadIdx.x; i < n;
       i += (size_t)gridDim.x * 256) {
    float4 a = o4[i];
    float4 b = p0[i], c = p1[i], d = p2[i];
    a.x += b.x + c.x + d.x;
    a.y += b.y + c.y + d.y;
    a.z += b.z + c.z + d.z;
    a.w += b.w + c.w + d.w;
    o4[i] = a;
  }
}

extern "C" void kernel_launch(void* const* d_in, const int* in_sizes, int n_in,
                              void* d_out, int out_size, void* d_ws, size_t ws_size,
                              hipStream_t stream) {
  const float* x = (const float*)d_in[0];
  const int* pw = (const int*)d_in[1];
  const float* scale = (const float*)d_in[2];
  float* out = (float*)d_out;

  ushort* xb = (ushort*)d_ws;  // 8 MiB
  float* rowsum = (float*)((char*)d_ws + (size_t)8 * 1024 * 1024);  // 4x512 f32
  const size_t need = (size_t)8 * 1024 * 1024 + 65536
      + (size_t)3 * BATCH * OUT_F * sizeof(float);  // ~56.3 MB
  float* part = (ws_size >= need)
      ? (float*)((char*)d_ws + (size_t)8 * 1024 * 1024 + 65536)
      : nullptr;

  cvt_rowsum<<<BATCH, 256, 0, stream>>>(x, xb, rowsum, part ? nullptr : out);
  dim3 grid(OUT_F / BN, BATCH / BM, KSPLIT);
  qgemm<<<grid, 256, 0, stream>>>(xb, pw, scale, rowsum, out, part);
  if (part) reduce_add<<<2048, 256, 0, stream>>>(out, part);
}